// Round 8
// baseline (1357.852 us; speedup 1.0000x reference)
//
#include <hip/hip_runtime.h>
#include <hip/hip_bf16.h>

typedef __bf16 bf16x8 __attribute__((ext_vector_type(8)));
typedef float f32x4 __attribute__((ext_vector_type(4)));
typedef unsigned int u32;
typedef unsigned short u16;
typedef unsigned long long u64;

#define T_ 512
#define E_ 256
#define U_ 512

// ---------------- workspace layout (bytes) ----------------
// xs_g : bf16 [T][64][256] (granule-swizzled rows)                 16 MiB
// w2   : bf16 [2 dir][32 us][4 wv][24 j][64 lane][8] frag-ordered   6 MiB
// hpub : u32  [2 dir][2 par][4 q][32 us][16 u][16 b] (h<<16|ep)   512 KiB
// hfin : f32  [2][64][512] (plain)                                256 KiB
static const size_t WS_XS = 0;
static const size_t WS_W2 = (size_t)16 << 20;
static const size_t WS_HP = WS_W2 + 6291456;
static const size_t WS_HF = WS_HP + 524288;

__device__ __forceinline__ float fsigm(float x) { return 1.f / (1.f + __expf(-x)); }
__device__ __forceinline__ float ftanh(float x) {
  float e = __expf(2.f * fabsf(x));
  float r = 1.f - 2.f / (e + 1.f);
  return copysignf(r, x);
}

// Embedding gather + bf16 convert + granule swizzle.
__global__ void embed_swz_kernel(const int* __restrict__ sent,
                                 const float* __restrict__ emb,
                                 __bf16* __restrict__ xs_g) {
  int id = blockIdx.x * 256 + threadIdx.x;
  int gx = id & 31;          // granule within row (32 x 8 bf16 = 256)
  int b  = (id >> 5) & 63;
  int t  = id >> 11;
  int idx = sent[b * T_ + t];            // sentence is [B][T]
  const float* src = emb + (size_t)idx * E_ + gx * 8;
  bf16x8 v;
#pragma unroll
  for (int j = 0; j < 8; ++j) v[j] = (__bf16)src[j];
  int gs = gx ^ (b & 7);                 // XOR swizzle keyed by batch row
  *(bf16x8*)(xs_g + (size_t)(t * 64 + b) * E_ + gs * 8) = v;
}

// Weight prep (fragment-ordered for direct coalesced global->reg in lstm_main)
// + zero-init of the self-validating h publication buffer (epochs cleared —
// required every call so stale epochs from a previous replay can never match).
// W-slice rows c = ul*4+gate (c in 0..63) per (dir, us in 0..31).
__global__ void __launch_bounds__(256)
wprep_kernel(const float* __restrict__ Wx_f, const float* __restrict__ Wh_f,
             const float* __restrict__ Wx_b, const float* __restrict__ Wh_b,
             __bf16* __restrict__ w2, u32* __restrict__ hpub) {
  int bid = blockIdx.x;              // ((d*32+us)*4+wv)*6 + jg
  int tid = threadIdx.x;
  {
    int zid = bid * 256 + tid;
    if (zid < 131072) hpub[zid] = 0u;
  }
  int jg = bid % 6;
  int wv = (bid / 6) & 3;
  int us = (bid / 24) & 31;
  int d  = bid / 768;
  int j    = jg * 4 + (tid >> 6);
  int lane = tid & 63;
  int c    = wv * 16 + (lane & 15);   // slice row 0..63
  int ul   = c >> 2, gate = c & 3;    // ul 0..15
  int n    = gate * 512 + us * 16 + ul;
  int k0   = j * 32 + (lane >> 4) * 8;
  const float* Wx = d ? Wx_b : Wx_f;
  const float* Wh = d ? Wh_b : Wh_f;
  bf16x8 v;
#pragma unroll
  for (int e = 0; e < 8; ++e) {
    int k = k0 + e;
    float f = (k < 256) ? Wx[(size_t)k * 2048 + n] : Wh[(size_t)(k - 256) * 2048 + n];
    v[e] = (__bf16)f;
  }
  size_t og = ((size_t)((d * 32 + us) * 4 + wv) * 24 + j) * 64 + lane;
  *(bf16x8*)(w2 + og * 8) = v;
}

// Persistent bidirectional LSTM. 256 WGs x 256 thr (4 waves; 1 WG/CU).
// WG = (dir, us 0..31, q 0..3): 16 units x 16 batches.
// z^T = W @ [x|h]^T ; D (m89): col=lane&15 (batch), row=(lane>>4)*4+i ->
// thread owns (unit ul=wv*4+kq, batch), acc[0..3]=i,f,g,o. Gates in regs.
// hpub slice ([16 u][16 b] u32 words): thread publishes its own word
// (coalesced relaxed agent atomic). Consumers: 16 coalesced u64 spec-loads
// per thread (4 producers x 4 consecutive units x 1 batch-pair), validate
// embedded epochs, retry on miss, pack -> 8 ds_write_b64 into swizzled hbuf.
// x-MFMAs run at the step TAIL (inside peers' publish-visibility window);
// h-MFMAs accumulate on top of the precomputed x-part.
__global__ void __launch_bounds__(256)
lstm_main(const __bf16* __restrict__ xs_g, const __bf16* __restrict__ w2,
          u32* __restrict__ hpub, float* __restrict__ hfin,
          const float* __restrict__ b_f, const float* __restrict__ b_b) {
  __shared__ __align__(16) __bf16 xbuf[2][16 * 256];   // 2 x 8 KiB
  __shared__ __align__(16) __bf16 hbuf[16 * 512];      // 16 KiB

  const int wg   = blockIdx.x;
  const int dir  = wg >> 7;
  const int sl   = wg & 127;
  const int us   = sl >> 2;            // 0..31
  const int q    = sl & 3;
  const int tid  = threadIdx.x;
  const int wv   = tid >> 6;           // 0..3 : W-row tile
  const int lane = tid & 63;
  const int bq_l = lane & 15;          // local batch / D col
  const int kq   = lane >> 4;          // k-quarter
  const int bsw  = bq_l & 7;           // swizzle key
  const int ul_own = wv * 4 + kq;      // owned local unit (0..15)
  const int u_own  = us * 16 + ul_own;
  const int b_own  = q * 16 + bq_l;

  // ---- weight fragments: direct coalesced global->reg ----
  bf16x8 wfrag[24];
  {
    const bf16x8* wp = (const bf16x8*)w2 +
                       ((size_t)((dir * 32 + us) * 4 + wv) * 24) * 64 + lane;
#pragma unroll
    for (int j = 0; j < 24; ++j) wfrag[j] = wp[j * 64];
  }

  const float* bias = dir ? b_b : b_f;
  const float bi  = bias[u_own];
  const float bff = bias[512 + u_own];
  const float bg  = bias[1024 + u_own];
  const float bo  = bias[1536 + u_own];
  float c_st = 0.f;

  // ---- producer word ptrs ([u][b]: word = ul*16 + b = wv*64 + lane) ----
  u32* const pw0 = hpub + ((size_t)(dir * 2 + 0) * 4 + q) * 8192 + us * 256 + wv * 64 + lane;
  u32* const pw1 = pw0 + 32768;

  // ---- consumer mapping: thread -> 4 producers x 4 consecutive u x b-pair ----
  const int b2  = tid & 7;             // batch pair (b = 2*b2, 2*b2+1)
  const int u0  = ((tid >> 3) & 3) * 4;
  const int ush = tid >> 5;            // 0..7; producer us_p = ush + 8J
  const u64* const cb = (const u64*)hpub + ((size_t)(dir * 2 + 0) * 4 + q) * 4096;
  int cde[4], cdo[4];
#pragma unroll
  for (int J = 0; J < 4; ++J) {
    int us_p = ush + 8 * J;
    int ga   = us_p * 2 + (u0 >> 3);   // global 8-unit granule 0..63
    int off  = (u0 & 7) * 2;
    int b0   = 2 * b2, b1 = 2 * b2 + 1;
    cde[J] = b0 * 1024 + ((ga ^ (b0 & 7)) << 4) + off;
    cdo[J] = b1 * 1024 + ((ga ^ (b1 & 7)) << 4) + off;
  }

  // ---- stage x_0 (8 KiB: 512 granules, 2 per thread) ----
  {
    int t0 = dir ? (T_ - 1) : 0;
    const uint4* xsrc = (const uint4*)(xs_g + ((size_t)t0 * 64 + q * 16) * 256);
    ((uint4*)xbuf[0])[tid] = xsrc[tid];
    ((uint4*)xbuf[0])[tid + 256] = xsrc[tid + 256];
  }
  __syncthreads();

  // ---- x-part MFMAs for t=0 ----
  f32x4 xacc0 = {0.f, 0.f, 0.f, 0.f};
  f32x4 xacc1 = {0.f, 0.f, 0.f, 0.f};
#pragma unroll
  for (int j = 0; j < 8; ++j) {
    int g = j * 4 + kq;
    bf16x8 a = *(const bf16x8*)(xbuf[0] + bq_l * 256 + ((g ^ bsw) << 3));
    if (j & 1) xacc1 = __builtin_amdgcn_mfma_f32_16x16x32_bf16(wfrag[j], a, xacc1, 0, 0, 0);
    else       xacc0 = __builtin_amdgcn_mfma_f32_16x16x32_bf16(wfrag[j], a, xacc0, 0, 0, 0);
  }

  for (int t = 0;; ++t) {
    const bool lastt = (t == T_ - 1);
    // ---- [P] speculative coalesced h loads (16 u64/thread) ----
    u64 v[16];
    const u64* csrc = cb + (size_t)(t & 1) * 16384;
    if (t > 0) {
#pragma unroll
      for (int J = 0; J < 4; ++J)
#pragma unroll
        for (int du = 0; du < 4; ++du)
          v[J * 4 + du] = __hip_atomic_load(
              csrc + (ush + 8 * J) * 128 + (u0 + du) * 8 + b2,
              __ATOMIC_RELAXED, __HIP_MEMORY_SCOPE_AGENT);
    }
    // ---- issue x_{t+1} global loads early ----
    uint4 xg0, xg1;
    if (!lastt) {
      const int teff = dir ? (T_ - 2 - t) : (t + 1);
      const uint4* xsrc = (const uint4*)(xs_g + ((size_t)teff * 64 + q * 16) * 256);
      xg0 = xsrc[tid];
      xg1 = xsrc[tid + 256];
    }

    f32x4 acc0 = xacc0;
    f32x4 acc1 = xacc1;

    if (t > 0) {
      // ---- [B] validate embedded epochs; retry until fresh ----
      const u32 ep = (u32)t;
      for (;;) {
        u32 bad = 0;
#pragma unroll
        for (int j = 0; j < 16; ++j)
          bad |= ((u32)v[j] ^ ep) | ((u32)(v[j] >> 32) ^ ep);
        bad &= 0xFFFFu;
        if (!__any((int)bad)) break;
        __builtin_amdgcn_s_sleep(1);
#pragma unroll
        for (int J = 0; J < 4; ++J)
#pragma unroll
          for (int du = 0; du < 4; ++du)
            v[J * 4 + du] = __hip_atomic_load(
                csrc + (ush + 8 * J) * 128 + (u0 + du) * 8 + b2,
                __ATOMIC_RELAXED, __HIP_MEMORY_SCOPE_AGENT);
      }
      // ---- [C] pack hi16s -> swizzled hbuf (8 x ds_write_b64) ----
#pragma unroll
      for (int J = 0; J < 4; ++J) {
        u64 we = 0, wo = 0;
#pragma unroll
        for (int du = 0; du < 4; ++du) {
          u64 x = v[J * 4 + du];
          we |= (u64)((u32)(x >> 16) & 0xFFFFu) << (16 * du);
          wo |= (u64)((u32)(x >> 48) & 0xFFFFu) << (16 * du);
        }
        *(u64*)((char*)hbuf + cde[J]) = we;
        *(u64*)((char*)hbuf + cdo[J]) = wo;
      }
      __syncthreads();   // S1: hbuf complete
      // ---- [D] h-part MFMAs (accumulate onto x-part) ----
#pragma unroll
      for (int j = 0; j < 16; ++j) {
        int g = j * 4 + kq;
        bf16x8 a = *(const bf16x8*)(hbuf + bq_l * 512 + ((g ^ bsw) << 3));
        if (j & 1) acc1 = __builtin_amdgcn_mfma_f32_16x16x32_bf16(wfrag[8 + j], a, acc1, 0, 0, 0);
        else       acc0 = __builtin_amdgcn_mfma_f32_16x16x32_bf16(wfrag[8 + j], a, acc0, 0, 0, 0);
      }
    }

    // ---- gates in registers ----
    const float zi = acc0[0] + acc1[0] + bi;
    const float zf = acc0[1] + acc1[1] + bff;
    const float zg = acc0[2] + acc1[2] + bg;
    const float zo = acc0[3] + acc1[3] + bo;
    c_st = fsigm(zf) * c_st + fsigm(zi) * ftanh(zg);
    const float hv = fsigm(zo) * ftanh(c_st);

    if (lastt) {
      hfin[(size_t)dir * 32768 + b_own * 512 + u_own] = hv;
      break;
    }

    // ---- [E] publish own word immediately (coalesced, fire-and-forget) ----
    {
      union { __bf16 h; u16 s; } cv;
      cv.h = (__bf16)hv;
      u32 word = ((u32)cv.s << 16) | (u32)(t + 1);
      __hip_atomic_store(((t + 1) & 1) ? pw1 : pw0, word, __ATOMIC_RELAXED,
                         __HIP_MEMORY_SCOPE_AGENT);
    }
    // ---- stage x_{t+1} (loads already in flight) ----
    {
      uint4* xdst = (uint4*)xbuf[(t + 1) & 1];
      xdst[tid] = xg0;
      xdst[tid + 256] = xg1;
    }
    __syncthreads();   // S2: xbuf ready; hbuf reads done

    // ---- tail: x-part MFMAs for step t+1 (overlap publish visibility) ----
    xacc0 = (f32x4){0.f, 0.f, 0.f, 0.f};
    xacc1 = (f32x4){0.f, 0.f, 0.f, 0.f};
    const __bf16* xb = xbuf[(t + 1) & 1];
#pragma unroll
    for (int j = 0; j < 8; ++j) {
      int g = j * 4 + kq;
      bf16x8 a = *(const bf16x8*)(xb + bq_l * 256 + ((g ^ bsw) << 3));
      if (j & 1) xacc1 = __builtin_amdgcn_mfma_f32_16x16x32_bf16(wfrag[j], a, xacc1, 0, 0, 0);
      else       xacc0 = __builtin_amdgcn_mfma_f32_16x16x32_bf16(wfrag[j], a, xacc0, 0, 0, 0);
    }
  }
}

// Final head: out = sigmoid((hcat @ W1 + b1) @ W2 + b2), all f32. One block.
__global__ void __launch_bounds__(1024)
dense_kernel(const float* __restrict__ hfin, const float* __restrict__ W1,
             const float* __restrict__ b1, const float* __restrict__ W2,
             const float* __restrict__ b2, float* __restrict__ out) {
  __shared__ float hid[64][64];
  const int t = threadIdx.x;
  const int b = t >> 4;
  const int jg = t & 15;           // 4 output cols each
  float a0 = b1[jg * 4 + 0], a1 = b1[jg * 4 + 1], a2 = b1[jg * 4 + 2], a3 = b1[jg * 4 + 3];
#pragma unroll 8
  for (int k = 0; k < 1024; ++k) {
    const float hv = hfin[(size_t)(k >> 9) * 32768 + b * 512 + (k & 511)];
    const float4 w = *(const float4*)(W1 + (size_t)k * 64 + jg * 4);
    a0 += hv * w.x; a1 += hv * w.y; a2 += hv * w.z; a3 += hv * w.w;
  }
  hid[b][jg * 4 + 0] = a0; hid[b][jg * 4 + 1] = a1;
  hid[b][jg * 4 + 2] = a2; hid[b][jg * 4 + 3] = a3;
  __syncthreads();
  if (t < 64) {
    float l = b2[0];
#pragma unroll 8
    for (int j = 0; j < 64; ++j) l += hid[t][j] * W2[j];
    out[t] = 1.f / (1.f + __expf(-l));
  }
}

extern "C" void kernel_launch(void* const* d_in, const int* in_sizes, int n_in,
                              void* d_out, int out_size, void* d_ws, size_t ws_size,
                              hipStream_t stream) {
  const int*   sent = (const int*)d_in[0];
  const float* emb  = (const float*)d_in[1];
  const float* Wx_f = (const float*)d_in[2];
  const float* Wh_f = (const float*)d_in[3];
  const float* b_f  = (const float*)d_in[4];
  const float* Wx_b = (const float*)d_in[5];
  const float* Wh_b = (const float*)d_in[6];
  const float* b_b  = (const float*)d_in[7];
  const float* W1   = (const float*)d_in[8];
  const float* b1   = (const float*)d_in[9];
  const float* W2   = (const float*)d_in[10];
  const float* b2   = (const float*)d_in[11];
  float* out = (float*)d_out;

  char* ws = (char*)d_ws;
  __bf16* xs_g = (__bf16*)(ws + WS_XS);
  __bf16* w2   = (__bf16*)(ws + WS_W2);
  u32*    hpub = (u32*)(ws + WS_HP);
  float*  hfin = (float*)(ws + WS_HF);

  hipLaunchKernelGGL(embed_swz_kernel, dim3(4096), dim3(256), 0, stream, sent, emb, xs_g);
  hipLaunchKernelGGL(wprep_kernel, dim3(1536), dim3(256), 0, stream,
                     Wx_f, Wh_f, Wx_b, Wh_b, w2, hpub);

  void* args[] = {(void*)&xs_g, (void*)&w2, (void*)&hpub, (void*)&hfin,
                  (void*)&b_f, (void*)&b_b};
  hipLaunchCooperativeKernel((void*)lstm_main, dim3(256), dim3(256), args, 0, stream);

  hipLaunchKernelGGL(dense_kernel, dim3(1), dim3(1024), 0, stream,
                     hfin, W1, b1, W2, b2, out);
}